// Round 16
// baseline (58.623 us; speedup 1.0000x reference)
//
#include <hip/hip_runtime.h>
#include <hip/hip_bf16.h>
#include <math.h>

#define N_ROWS 8192
#define D_DIM  256
#define BM 128
#define BN 64
#define JSPLIT 8
#define JRANGE (N_ROWS / JSPLIT)     // 1024
#define NT (JRANGE / BN)             // 16 j-steps per block

typedef __attribute__((ext_vector_type(4))) float f32x4;
typedef __attribute__((ext_vector_type(4))) int   i32x4;
typedef __attribute__((ext_vector_type(8))) int   i32x8;

// total scale: exp(dot*2) == exp2(dot * 2*log2(e)); sqrt folded onto A and B
#define CAST_SCALE 1.6986388f        // sqrt(2 * log2(e))
#define SCALE_ONE 127                // E8M0 exponent bias -> multiplier 1.0

__device__ __forceinline__ float fast_exp2(float x) {
#if __has_builtin(__builtin_amdgcn_exp2f)
    return __builtin_amdgcn_exp2f(x);
#else
    return exp2f(x);
#endif
}

// ------- kernel 1: L2-normalize rows, scale, cast to fp8 e4m3 (+ zero accum) -
__global__ void norm_cast_kernel(const float* __restrict__ out0,
                                 const float* __restrict__ out1,
                                 unsigned char* __restrict__ a_f8,
                                 unsigned char* __restrict__ b_f8,
                                 float* __restrict__ zero_me,   // pos+all, 2*N floats
                                 float* __restrict__ out) {
    int gtid = blockIdx.x * blockDim.x + threadIdx.x;
    if (gtid < 2 * N_ROWS) zero_me[gtid] = 0.0f;
    if (gtid == 0) out[0] = 0.0f;     // loss kernel accumulates atomically

    int wave = gtid >> 6;
    int lane = threadIdx.x & 63;
    const float* src    = (wave < N_ROWS) ? out0 : out1;
    unsigned char* dst  = (wave < N_ROWS) ? a_f8 : b_f8;
    int row = (wave < N_ROWS) ? wave : wave - N_ROWS;

    float4 v = *reinterpret_cast<const float4*>(src + (size_t)row * D_DIM + lane * 4);
    float ss = v.x * v.x + v.y * v.y + v.z * v.z + v.w * v.w;
    #pragma unroll
    for (int off = 32; off; off >>= 1) ss += __shfl_xor(ss, off);
    float inv = CAST_SCALE / fmaxf(sqrtf(ss), 1e-12f);

    int packed = __builtin_amdgcn_cvt_pk_fp8_f32(v.x * inv, v.y * inv, 0, 0);
    packed     = __builtin_amdgcn_cvt_pk_fp8_f32(v.z * inv, v.w * inv, packed, 1);
    *reinterpret_cast<unsigned int*>(dst + (size_t)row * D_DIM + lane * 4) =
        (unsigned int)packed;
}

// ------- kernel 2: MX-fp8 K=128 fused GEMM + exp2 + masked row-sums ---------
// r15 schedule (triple-buffer, counted vmcnt, raw s_barrier, MX-scaled fp8
// K=128 with unit scales) widened to 512-thread blocks: 8 waves = 2 row-bands
// x 4 col-strips, wave-tile 64x16 -> 4 waves/SIMD guaranteed in-block, so one
// wave's MFMA hides another's exp2 epilogue. Per-CU instruction totals
// unchanged; VGPR ~104; LDS 3x16KB x 2 blocks/CU = 96KB.
__global__ __launch_bounds__(512, 2)
void fused_flash_kernel(const unsigned char* __restrict__ A,
                        const unsigned char* __restrict__ B,
                        const int* __restrict__ labels,
                        float* __restrict__ pos_sum,
                        float* __restrict__ all_sum) {
    __shared__ unsigned char Bs[3][BN * D_DIM];   // 3 x 16 KB

    const int tid    = threadIdx.x;
    const int lane   = tid & 63;
    const int wid    = tid >> 6;        // 0..7
    const int wr     = wid >> 2;        // 0..1  (64-row band)
    const int wq     = wid & 3;         // 0..3  (16-col strip)
    const int lane16 = lane & 15;
    const int kgrp   = lane >> 4;       // 0..3

    const int jsplit = blockIdx.x & 7;
    const int rowt   = blockIdx.x >> 3;
    const int i0     = rowt * BM;
    const int jbase  = jsplit * JRANGE;

    // ---- A fragments -> registers (once), PINNED (64 VGPR fp8) ----
    // af[m][h]: row = i0+wr*64+m*16+lane16, k bytes [h*128 + kgrp*32, +32)
    i32x8 af[4][2];
    #pragma unroll
    for (int m = 0; m < 4; ++m) {
        const unsigned char* ap =
            A + (size_t)(i0 + wr * 64 + m * 16 + lane16) * D_DIM + kgrp * 32;
        #pragma unroll
        for (int h = 0; h < 2; ++h) {
            i32x4 lo = *reinterpret_cast<const i32x4*>(ap + h * 128);
            i32x4 hi = *reinterpret_cast<const i32x4*>(ap + h * 128 + 16);
            af[m][h] = __builtin_shufflevector(lo, hi, 0, 1, 2, 3, 4, 5, 6, 7);
        }
    }
    #pragma unroll
    for (int m = 0; m < 4; ++m)
        #pragma unroll
        for (int h = 0; h < 2; ++h)
            asm volatile("" : "+v"(af[m][h]));

    // row labels (0..99 fit in a byte), packed 4-per-int, pinned
    int labp[4];
    #pragma unroll
    for (int m = 0; m < 4; ++m) {
        int4 v = *reinterpret_cast<const int4*>(labels + i0 + wr * 64 + m * 16 + kgrp * 4);
        labp[m] = v.x | (v.y << 8) | (v.z << 16) | (v.w << 24);
        asm volatile("" : "+v"(labp[m]));
    }

    // ---- B staging: 16 chunks of 1KB (4 rows x 256B), 2 per wave ----
    // LDS[row][phys] = global[row][phys ^ (row&15)]  (16B slots, 16 per row)
    auto stage = [&](int buf, int t) {
        const int jrow0 = jbase + t * BN;
        #pragma unroll
        for (int cc = 0; cc < 2; ++cc) {
            int c  = wid * 2 + cc;                  // chunk 0..15 (wave-uniform)
            int gr = jrow0 + c * 4 + kgrp;          // global B row
            const unsigned char* src =
                B + (size_t)gr * D_DIM + ((lane16 ^ (gr & 15)) << 4);
            __builtin_amdgcn_global_load_lds(
                (const __attribute__((address_space(1))) void*)src,
                (__attribute__((address_space(3))) void*)(&Bs[buf][0] + c * 1024),
                16, 0, 0);
        }
    };

    float allp[4][4] = {};
    float posp[4][4] = {};

    // prologue: stage tiles 0 and 1; drain tile 0 only (vmcnt(2) leaves tile 1)
    stage(0, 0);
    stage(1, 1);
    asm volatile("s_waitcnt vmcnt(2)" ::: "memory");
    __builtin_amdgcn_sched_barrier(0);
    __builtin_amdgcn_s_barrier();
    __builtin_amdgcn_sched_barrier(0);

    int cur = 0;
    for (int t = 0; t < NT; ++t) {
        // column label early (hides under MFMA)
        const int labc = labels[jbase + t * BN + wq * 16 + lane16];

        // ---- hoist the 4 b128 B-loads (2 x i32x8 operands), then 8 MFMAs ----
        const int tr = wq * 16 + lane16;              // B row (output col)
        i32x8 bv[2];
        #pragma unroll
        for (int h = 0; h < 2; ++h) {
            int g0 = h * 8 + kgrp * 2;                // logical 16B slot
            i32x4 lo = *reinterpret_cast<const i32x4*>(
                &Bs[cur][0] + tr * 256 + ((g0 ^ lane16) << 4));
            i32x4 hi = *reinterpret_cast<const i32x4*>(
                &Bs[cur][0] + tr * 256 + (((g0 + 1) ^ lane16) << 4));
            bv[h] = __builtin_shufflevector(lo, hi, 0, 1, 2, 3, 4, 5, 6, 7);
        }

        f32x4 acc[4] = {};
        __builtin_amdgcn_s_setprio(1);
        #pragma unroll
        for (int h = 0; h < 2; ++h)
            #pragma unroll
            for (int m = 0; m < 4; ++m)
                acc[m] = __builtin_amdgcn_mfma_scale_f32_16x16x128_f8f6f4(
                    af[m][h], bv[h], acc[m],
                    0, 0,                     // cbsz=fp8(e4m3), blgp=fp8
                    0, SCALE_ONE,             // A scale: opsel 0, x1.0
                    0, SCALE_ONE);            // B scale: opsel 0, x1.0
        __builtin_amdgcn_s_setprio(0);

        // stage 2 tiles ahead into the buffer freed at step t-1
        if (t + 2 < NT) stage((cur + 2) % 3, t + 2);

        if (t < NT - 1) {
            // counted drain: stage(t+1) complete; stage(t+2) stays in flight.
            if (t + 2 < NT) asm volatile("s_waitcnt vmcnt(2)" ::: "memory");
            else            asm volatile("s_waitcnt vmcnt(0)" ::: "memory");
            __builtin_amdgcn_sched_barrier(0);
            __builtin_amdgcn_s_barrier();
            __builtin_amdgcn_sched_barrier(0);
        }

        // ---- epilogue: exp2 + mask, accumulate row sums in registers ----
        #pragma unroll
        for (int m = 0; m < 4; ++m) {
            #pragma unroll
            for (int r = 0; r < 4; ++r) {
                float e = fast_exp2(acc[m][r]);       // == exp(logit/T)
                allp[m][r] += e;
                int lr = (labp[m] >> (r * 8)) & 0xFF;
                posp[m][r] += (lr == labc) ? e : 0.0f;
            }
        }

        cur = (cur + 1) % 3;
    }

    // ---- final: reduce across the 16 col-lanes, one atomic per row ----
    #pragma unroll
    for (int m = 0; m < 4; ++m) {
        #pragma unroll
        for (int r = 0; r < 4; ++r) {
            float a = allp[m][r], p = posp[m][r];
            #pragma unroll
            for (int off = 1; off < 16; off <<= 1) {
                a += __shfl_xor(a, off);
                p += __shfl_xor(p, off);
            }
            if (lane16 == 0) {
                int grow = i0 + wr * 64 + m * 16 + kgrp * 4 + r;
                atomicAdd(&all_sum[grow], a);
                atomicAdd(&pos_sum[grow], p);
            }
        }
    }
}

// ------- kernel 3: parallel loss reduction (out pre-zeroed by norm_cast) ----
__global__ void loss_kernel(const float* __restrict__ pos_sum,
                            const float* __restrict__ all_sum,
                            float* __restrict__ out) {
    int gid = blockIdx.x * blockDim.x + threadIdx.x;
    float acc = 0.0f;
    for (int i = gid; i < N_ROWS; i += gridDim.x * blockDim.x)
        acc += logf(pos_sum[i] / all_sum[i]);
    #pragma unroll
    for (int off = 32; off; off >>= 1) acc += __shfl_xor(acc, off);
    __shared__ float red[8];
    int wv = threadIdx.x >> 6, lane = threadIdx.x & 63;
    if (lane == 0) red[wv] = acc;
    __syncthreads();
    if (threadIdx.x == 0) {
        float s = 0.0f;
        #pragma unroll
        for (int w = 0; w < 8; ++w) s += red[w];
        atomicAdd(out, -s / (float)N_ROWS);
    }
}

// ---------------- launch -----------------------------------------------------
extern "C" void kernel_launch(void* const* d_in, const int* in_sizes, int n_in,
                              void* d_out, int out_size, void* d_ws, size_t ws_size,
                              hipStream_t stream) {
    const float* out0   = (const float*)d_in[0];
    const float* out1   = (const float*)d_in[1];
    const int*   labels = (const int*)d_in[2];
    float*       out    = (float*)d_out;

    unsigned char* a_f8 = (unsigned char*)d_ws;
    unsigned char* b_f8 = a_f8 + (size_t)N_ROWS * D_DIM;
    float* pos  = (float*)(b_f8 + (size_t)N_ROWS * D_DIM);
    float* alls = pos + N_ROWS;

    norm_cast_kernel<<<2 * N_ROWS / 4, 256, 0, stream>>>(out0, out1, a_f8, b_f8, pos, out);

    fused_flash_kernel<<<JSPLIT * (N_ROWS / BM), 512, 0, stream>>>(a_f8, b_f8, labels, pos, alls);

    loss_kernel<<<16, 512, 0, stream>>>(pos, alls, out);
}

// Round 17
// 44.043 us; speedup vs baseline: 1.3310x; 1.3310x over previous
//
#include <hip/hip_runtime.h>
#include <hip/hip_bf16.h>
#include <math.h>

#define N_ROWS 8192
#define D_DIM  256
#define BM 128
#define BN 64
#define JSPLIT 8
#define JRANGE (N_ROWS / JSPLIT)     // 1024
#define NT (JRANGE / BN)             // 16 j-steps per block

typedef __attribute__((ext_vector_type(4))) float f32x4;
typedef __attribute__((ext_vector_type(4))) int   i32x4;
typedef __attribute__((ext_vector_type(8))) int   i32x8;

// total scale: exp(dot*2) == exp2(dot * 2*log2(e)); sqrt folded onto A and B
#define CAST_SCALE 1.6986388f        // sqrt(2 * log2(e))
#define SCALE_ONE 127                // E8M0 exponent bias -> multiplier 1.0

__device__ __forceinline__ float fast_exp2(float x) {
#if __has_builtin(__builtin_amdgcn_exp2f)
    return __builtin_amdgcn_exp2f(x);
#else
    return exp2f(x);
#endif
}

// ------- kernel 1: L2-normalize rows, scale, cast to fp8 e4m3 (+ zero accum) -
__global__ void norm_cast_kernel(const float* __restrict__ out0,
                                 const float* __restrict__ out1,
                                 unsigned char* __restrict__ a_f8,
                                 unsigned char* __restrict__ b_f8,
                                 float* __restrict__ zero_me,   // pos+all, 2*N floats
                                 float* __restrict__ out) {
    int gtid = blockIdx.x * blockDim.x + threadIdx.x;
    if (gtid < 2 * N_ROWS) zero_me[gtid] = 0.0f;
    if (gtid == 0) out[0] = 0.0f;     // loss kernel accumulates atomically

    int wave = gtid >> 6;
    int lane = threadIdx.x & 63;
    const float* src    = (wave < N_ROWS) ? out0 : out1;
    unsigned char* dst  = (wave < N_ROWS) ? a_f8 : b_f8;
    int row = (wave < N_ROWS) ? wave : wave - N_ROWS;

    float4 v = *reinterpret_cast<const float4*>(src + (size_t)row * D_DIM + lane * 4);
    float ss = v.x * v.x + v.y * v.y + v.z * v.z + v.w * v.w;
    #pragma unroll
    for (int off = 32; off; off >>= 1) ss += __shfl_xor(ss, off);
    float inv = CAST_SCALE / fmaxf(sqrtf(ss), 1e-12f);

    int packed = __builtin_amdgcn_cvt_pk_fp8_f32(v.x * inv, v.y * inv, 0, 0);
    packed     = __builtin_amdgcn_cvt_pk_fp8_f32(v.z * inv, v.w * inv, packed, 1);
    *reinterpret_cast<unsigned int*>(dst + (size_t)row * D_DIM + lane * 4) =
        (unsigned int)packed;
}

// ------- kernel 2: MX-fp8 K=128 fused GEMM + deferred exp2 epilogue ---------
// r15 structure (4 waves 2x2, wave-tile 64x32, triple-buffer, counted vmcnt,
// MX-scaled fp8 K=128 unit scales) + T15 deferred epilogue: two acc sets,
// step t's exp2+mask runs during step t+1, textually between the ds_read
// issue and the MFMA cluster, so trans/VALU overlaps LDS latency and the
// other wave's matrix-pipe time.

#define BV_LOAD(BV)                                                            \
    _Pragma("unroll")                                                          \
    for (int n = 0; n < 2; ++n) {                                              \
        const int tr = wc * 32 + n * 16 + lane16;                              \
        _Pragma("unroll")                                                      \
        for (int h = 0; h < 2; ++h) {                                          \
            int g0 = h * 8 + kgrp * 2;                                         \
            i32x4 lo = *reinterpret_cast<const i32x4*>(                        \
                &Bs[cur][0] + tr * 256 + ((g0 ^ lane16) << 4));                \
            i32x4 hi = *reinterpret_cast<const i32x4*>(                        \
                &Bs[cur][0] + tr * 256 + (((g0 + 1) ^ lane16) << 4));          \
            BV[n][h] = __builtin_shufflevector(lo, hi, 0, 1, 2, 3, 4, 5, 6, 7);\
        }                                                                      \
    }

#define MFMA_BLOCK(ACC, BV)                                                    \
    __builtin_amdgcn_s_setprio(1);                                             \
    _Pragma("unroll")                                                          \
    for (int m = 0; m < 4; ++m)                                                \
        _Pragma("unroll")                                                      \
        for (int n = 0; n < 2; ++n) {                                          \
            ACC[m][n] = __builtin_amdgcn_mfma_scale_f32_16x16x128_f8f6f4(      \
                af[m][0], BV[n][0], zero4, 0, 0, 0, SCALE_ONE, 0, SCALE_ONE);  \
            ACC[m][n] = __builtin_amdgcn_mfma_scale_f32_16x16x128_f8f6f4(      \
                af[m][1], BV[n][1], ACC[m][n], 0, 0, 0, SCALE_ONE, 0, SCALE_ONE);\
        }                                                                      \
    __builtin_amdgcn_s_setprio(0);

#define EPILOGUE(ACC, LC0, LC1)                                                \
    _Pragma("unroll")                                                          \
    for (int m = 0; m < 4; ++m) {                                              \
        _Pragma("unroll")                                                      \
        for (int r = 0; r < 4; ++r) {                                          \
            float e0 = fast_exp2(ACC[m][0][r]);                                \
            float e1 = fast_exp2(ACC[m][1][r]);                                \
            allp[m][r] += e0 + e1;                                             \
            int lr = (labp[m] >> (r * 8)) & 0xFF;                              \
            posp[m][r] += ((lr == (LC0)) ? e0 : 0.0f)                          \
                        + ((lr == (LC1)) ? e1 : 0.0f);                         \
        }                                                                      \
    }

#define SYNC_STEP(T)                                                           \
    if ((T) + 2 < NT) stage((cur + 2) % 3, (T) + 2);                           \
    if ((T) < NT - 1) {                                                        \
        if ((T) + 2 < NT) asm volatile("s_waitcnt vmcnt(4)" ::: "memory");     \
        else              asm volatile("s_waitcnt vmcnt(0)" ::: "memory");     \
        __builtin_amdgcn_sched_barrier(0);                                     \
        __builtin_amdgcn_s_barrier();                                          \
        __builtin_amdgcn_sched_barrier(0);                                     \
    }                                                                          \
    cur = (cur + 1) % 3;

__global__ __launch_bounds__(256, 2)
void fused_flash_kernel(const unsigned char* __restrict__ A,
                        const unsigned char* __restrict__ B,
                        const int* __restrict__ labels,
                        float* __restrict__ pos_sum,
                        float* __restrict__ all_sum) {
    __shared__ unsigned char Bs[3][BN * D_DIM];   // 3 x 16 KB

    const int tid    = threadIdx.x;
    const int lane   = tid & 63;
    const int wid    = tid >> 6;        // 0..3
    const int wr     = wid >> 1;        // 0..1  (64-row band)
    const int wc     = wid & 1;         // 0..1  (32-col half)
    const int lane16 = lane & 15;
    const int kgrp   = lane >> 4;       // 0..3

    const int jsplit = blockIdx.x & 7;
    const int rowt   = blockIdx.x >> 3;
    const int i0     = rowt * BM;
    const int jbase  = jsplit * JRANGE;

    const f32x4 zero4 = {};

    // ---- A fragments -> registers (once), PINNED (64 VGPR fp8) ----
    i32x8 af[4][2];
    #pragma unroll
    for (int m = 0; m < 4; ++m) {
        const unsigned char* ap =
            A + (size_t)(i0 + wr * 64 + m * 16 + lane16) * D_DIM + kgrp * 32;
        #pragma unroll
        for (int h = 0; h < 2; ++h) {
            i32x4 lo = *reinterpret_cast<const i32x4*>(ap + h * 128);
            i32x4 hi = *reinterpret_cast<const i32x4*>(ap + h * 128 + 16);
            af[m][h] = __builtin_shufflevector(lo, hi, 0, 1, 2, 3, 4, 5, 6, 7);
        }
    }
    #pragma unroll
    for (int m = 0; m < 4; ++m)
        #pragma unroll
        for (int h = 0; h < 2; ++h)
            asm volatile("" : "+v"(af[m][h]));

    // row labels (0..99 fit in a byte), packed 4-per-int, pinned
    int labp[4];
    #pragma unroll
    for (int m = 0; m < 4; ++m) {
        int4 v = *reinterpret_cast<const int4*>(labels + i0 + wr * 64 + m * 16 + kgrp * 4);
        labp[m] = v.x | (v.y << 8) | (v.z << 16) | (v.w << 24);
        asm volatile("" : "+v"(labp[m]));
    }

    // ---- B staging: 16 chunks of 1KB (4 rows x 256B), 4 per wave ----
    auto stage = [&](int buf, int t) {
        const int jrow0 = jbase + t * BN;
        #pragma unroll
        for (int cc = 0; cc < 4; ++cc) {
            int c  = wid * 4 + cc;                  // chunk 0..15 (wave-uniform)
            int gr = jrow0 + c * 4 + kgrp;          // global B row
            const unsigned char* src =
                B + (size_t)gr * D_DIM + ((lane16 ^ (gr & 15)) << 4);
            __builtin_amdgcn_global_load_lds(
                (const __attribute__((address_space(1))) void*)src,
                (__attribute__((address_space(3))) void*)(&Bs[buf][0] + c * 1024),
                16, 0, 0);
        }
    };

    float allp[4][4] = {};
    float posp[4][4] = {};
    f32x4 accA[4][2], accB[4][2];
    int lcA0 = 0, lcA1 = 0, lcB0 = 0, lcB1 = 0;

    // prologue: stage tiles 0 and 1; drain tile 0 only
    stage(0, 0);
    stage(1, 1);
    asm volatile("s_waitcnt vmcnt(4)" ::: "memory");
    __builtin_amdgcn_sched_barrier(0);
    __builtin_amdgcn_s_barrier();
    __builtin_amdgcn_sched_barrier(0);

    int cur = 0;

    // ---- step 0 -> accA (no deferred epilogue yet) ----
    {
        const int jc = jbase + 0 * BN + wc * 32 + lane16;
        lcA0 = labels[jc];
        lcA1 = labels[jc + 16];
        i32x8 bv[2][2];
        BV_LOAD(bv);
        MFMA_BLOCK(accA, bv);
        SYNC_STEP(0);
    }

    // ---- steps 1..NT-1, two per iteration (static acc roles) ----
    for (int tt = 1; tt < NT; tt += 2) {
        {   // step tt -> accB; epilogue of step tt-1 (accA)
            const int jc = jbase + tt * BN + wc * 32 + lane16;
            lcB0 = labels[jc];
            lcB1 = labels[jc + 16];
            i32x8 bv[2][2];
            BV_LOAD(bv);
            EPILOGUE(accA, lcA0, lcA1);
            MFMA_BLOCK(accB, bv);
            SYNC_STEP(tt);
        }
        if (tt + 1 < NT) {   // step tt+1 -> accA; epilogue of step tt (accB)
            const int t2 = tt + 1;
            const int jc = jbase + t2 * BN + wc * 32 + lane16;
            lcA0 = labels[jc];
            lcA1 = labels[jc + 16];
            i32x8 bv[2][2];
            BV_LOAD(bv);
            EPILOGUE(accB, lcB0, lcB1);
            MFMA_BLOCK(accA, bv);
            SYNC_STEP(t2);
        }
    }
    // NT even -> last computed step (NT-1) sits in accB
    EPILOGUE(accB, lcB0, lcB1);

    // ---- final: reduce across the 16 col-lanes, one atomic per row ----
    #pragma unroll
    for (int m = 0; m < 4; ++m) {
        #pragma unroll
        for (int r = 0; r < 4; ++r) {
            float a = allp[m][r], p = posp[m][r];
            #pragma unroll
            for (int off = 1; off < 16; off <<= 1) {
                a += __shfl_xor(a, off);
                p += __shfl_xor(p, off);
            }
            if (lane16 == 0) {
                int grow = i0 + wr * 64 + m * 16 + kgrp * 4 + r;
                atomicAdd(&all_sum[grow], a);
                atomicAdd(&pos_sum[grow], p);
            }
        }
    }
}

// ------- kernel 3: parallel loss reduction (out pre-zeroed by norm_cast) ----
__global__ void loss_kernel(const float* __restrict__ pos_sum,
                            const float* __restrict__ all_sum,
                            float* __restrict__ out) {
    int gid = blockIdx.x * blockDim.x + threadIdx.x;
    float acc = 0.0f;
    for (int i = gid; i < N_ROWS; i += gridDim.x * blockDim.x)
        acc += logf(pos_sum[i] / all_sum[i]);
    #pragma unroll
    for (int off = 32; off; off >>= 1) acc += __shfl_xor(acc, off);
    __shared__ float red[8];
    int wv = threadIdx.x >> 6, lane = threadIdx.x & 63;
    if (lane == 0) red[wv] = acc;
    __syncthreads();
    if (threadIdx.x == 0) {
        float s = 0.0f;
        #pragma unroll
        for (int w = 0; w < 8; ++w) s += red[w];
        atomicAdd(out, -s / (float)N_ROWS);
    }
}

// ---------------- launch -----------------------------------------------------
extern "C" void kernel_launch(void* const* d_in, const int* in_sizes, int n_in,
                              void* d_out, int out_size, void* d_ws, size_t ws_size,
                              hipStream_t stream) {
    const float* out0   = (const float*)d_in[0];
    const float* out1   = (const float*)d_in[1];
    const int*   labels = (const int*)d_in[2];
    float*       out    = (float*)d_out;

    unsigned char* a_f8 = (unsigned char*)d_ws;
    unsigned char* b_f8 = a_f8 + (size_t)N_ROWS * D_DIM;
    float* pos  = (float*)(b_f8 + (size_t)N_ROWS * D_DIM);
    float* alls = pos + N_ROWS;

    norm_cast_kernel<<<2 * N_ROWS / 4, 256, 0, stream>>>(out0, out1, a_f8, b_f8, pos, out);

    fused_flash_kernel<<<JSPLIT * (N_ROWS / BM), 256, 0, stream>>>(a_f8, b_f8, labels, pos, alls);

    loss_kernel<<<16, 512, 0, stream>>>(pos, alls, out);
}

// Round 18
// 36.595 us; speedup vs baseline: 1.6020x; 1.2035x over previous
//
#include <hip/hip_runtime.h>
#include <hip/hip_bf16.h>
#include <math.h>

#define N_ROWS 8192
#define D_DIM  256                   // elements; fp4 row = 128 bytes
#define ROWB   128                   // bytes per fp4 row
#define BM 128
#define BN 64
#define JSPLIT 8
#define JRANGE (N_ROWS / JSPLIT)     // 1024
#define NT (JRANGE / BN)             // 16 j-steps per block

typedef __attribute__((ext_vector_type(4))) float f32x4;
typedef __attribute__((ext_vector_type(4))) int   i32x4;
typedef __attribute__((ext_vector_type(8))) int   i32x8;

// logit = dot(na,nb)*2 ; exp(logit) = exp2(dot * 2*log2e).
// fp4 path: quantize na*G with G = sqrt(2*log2e*256) = 27.178; HW scales
// 2^-4 * 2^-4 = 2^-8 -> D = dot * G^2/256 = dot * 2*log2e. exp2(D) direct.
#define CAST_G    27.17835f
#define SCALE_Q16 123                // E8M0: 2^(123-127) = 2^-4

__device__ __forceinline__ float fast_exp2(float x) {
#if __has_builtin(__builtin_amdgcn_exp2f)
    return __builtin_amdgcn_exp2f(x);
#else
    return exp2f(x);
#endif
}

// branchless fp4 e2m1 encode (codes {0,.5,1,1.5,2,3,4,6} are monotone)
__device__ __forceinline__ unsigned int enc_fp4(float x) {
    float a = fabsf(x);
    unsigned int s = (__float_as_uint(x) >> 31) << 3;
    unsigned int c = (a > 0.25f) + (a > 0.75f) + (a > 1.25f) + (a > 1.75f)
                   + (a > 2.5f)  + (a > 3.5f)  + (a > 5.0f);
    return s | c;
}

// ------- kernel 1: L2-normalize rows, scale, cast to fp4 e2m1 (+ zero accum) -
__global__ void norm_cast_kernel(const float* __restrict__ out0,
                                 const float* __restrict__ out1,
                                 unsigned char* __restrict__ a_f4,
                                 unsigned char* __restrict__ b_f4,
                                 float* __restrict__ zero_me,   // pos+all, 2*N floats
                                 float* __restrict__ out) {
    int gtid = blockIdx.x * blockDim.x + threadIdx.x;
    if (gtid < 2 * N_ROWS) zero_me[gtid] = 0.0f;
    if (gtid == 0) out[0] = 0.0f;     // loss kernel accumulates atomically

    int wave = gtid >> 6;
    int lane = threadIdx.x & 63;
    const float* src    = (wave < N_ROWS) ? out0 : out1;
    unsigned char* dst  = (wave < N_ROWS) ? a_f4 : b_f4;
    int row = (wave < N_ROWS) ? wave : wave - N_ROWS;

    float4 v = *reinterpret_cast<const float4*>(src + (size_t)row * D_DIM + lane * 4);
    float ss = v.x * v.x + v.y * v.y + v.z * v.z + v.w * v.w;
    #pragma unroll
    for (int off = 32; off; off >>= 1) ss += __shfl_xor(ss, off);
    float inv = CAST_G / fmaxf(sqrtf(ss), 1e-12f);

    unsigned int p = enc_fp4(v.x * inv)
                   | (enc_fp4(v.y * inv) << 4)
                   | (enc_fp4(v.z * inv) << 8)
                   | (enc_fp4(v.w * inv) << 12);
    *reinterpret_cast<unsigned short*>(dst + (size_t)row * ROWB + lane * 2) =
        (unsigned short)p;
}

// ------- kernel 2: MX-fp4 K=128 fused GEMM + exp2 + masked row-sums ---------
// r15 structure (4 waves 2x2, wave-tile 64x32, triple-buffer, counted vmcnt,
// raw s_barrier) with fp4 e2m1 operands: MFMA pipe 1107->714 cyc/SIMD/step,
// LDS reads 8->4 b128, staging/FETCH halved. Swizzle: 8x16B slots per 128B
// row, LDS[r][phys] = global[r][phys ^ (r&7)]; reads phys = g ^ (tr&7) ->
// conflict-free within each 8-row group.
__global__ __launch_bounds__(256, 2)
void fused_flash_kernel(const unsigned char* __restrict__ A,
                        const unsigned char* __restrict__ B,
                        const int* __restrict__ labels,
                        float* __restrict__ pos_sum,
                        float* __restrict__ all_sum) {
    __shared__ unsigned char Bs[3][BN * ROWB];   // 3 x 8 KB

    const int tid    = threadIdx.x;
    const int lane   = tid & 63;
    const int wid    = tid >> 6;        // 0..3
    const int wr     = wid >> 1;        // 0..1  (64-row band)
    const int wc     = wid & 1;         // 0..1  (32-col half)
    const int lane16 = lane & 15;
    const int kgrp   = lane >> 4;       // 0..3

    const int jsplit = blockIdx.x & 7;
    const int rowt   = blockIdx.x >> 3;
    const int i0     = rowt * BM;
    const int jbase  = jsplit * JRANGE;

    const i32x4 zeros = {0, 0, 0, 0};

    // ---- A fragments -> registers (once), PINNED (32 VGPR fp4) ----
    // af[m][h]: row = i0+wr*64+m*16+lane16, K [h*128+kgrp*32, +32) = 16 bytes
    i32x4 af[4][2];
    #pragma unroll
    for (int m = 0; m < 4; ++m) {
        const unsigned char* ap =
            A + (size_t)(i0 + wr * 64 + m * 16 + lane16) * ROWB + kgrp * 16;
        #pragma unroll
        for (int h = 0; h < 2; ++h)
            af[m][h] = *reinterpret_cast<const i32x4*>(ap + h * 64);
    }
    #pragma unroll
    for (int m = 0; m < 4; ++m)
        #pragma unroll
        for (int h = 0; h < 2; ++h)
            asm volatile("" : "+v"(af[m][h]));

    // row labels (0..99 fit in a byte), packed 4-per-int, pinned
    int labp[4];
    #pragma unroll
    for (int m = 0; m < 4; ++m) {
        int4 v = *reinterpret_cast<const int4*>(labels + i0 + wr * 64 + m * 16 + kgrp * 4);
        labp[m] = v.x | (v.y << 8) | (v.z << 16) | (v.w << 24);
        asm volatile("" : "+v"(labp[m]));
    }

    // ---- B staging: tile 8KB = 8 chunks of 1KB (8 rows x 128B), 2 per wave --
    auto stage = [&](int buf, int t) {
        const int jrow0 = jbase + t * BN;
        #pragma unroll
        for (int cc = 0; cc < 2; ++cc) {
            int c  = wid * 2 + cc;                  // chunk 0..7 (wave-uniform)
            int gr = jrow0 + c * 8 + (lane >> 3);   // global B row
            const unsigned char* src =
                B + (size_t)gr * ROWB + (((lane & 7) ^ (gr & 7)) << 4);
            __builtin_amdgcn_global_load_lds(
                (const __attribute__((address_space(1))) void*)src,
                (__attribute__((address_space(3))) void*)(&Bs[buf][0] + c * 1024),
                16, 0, 0);
        }
    };

    float allp[4][4] = {};
    float posp[4][4] = {};

    // prologue: stage tiles 0 and 1; drain tile 0 only (vmcnt(2) leaves tile 1)
    stage(0, 0);
    stage(1, 1);
    asm volatile("s_waitcnt vmcnt(2)" ::: "memory");
    __builtin_amdgcn_sched_barrier(0);
    __builtin_amdgcn_s_barrier();
    __builtin_amdgcn_sched_barrier(0);

    int cur = 0;
    for (int t = 0; t < NT; ++t) {
        // column labels early (hide under MFMA)
        const int jc    = jbase + t * BN + wc * 32 + lane16;
        const int labc0 = labels[jc];
        const int labc1 = labels[jc + 16];

        // ---- 4 b128 B-loads, then 16 MFMAs ----
        i32x4 bv[2][2];
        #pragma unroll
        for (int n = 0; n < 2; ++n) {
            const int tr = wc * 32 + n * 16 + lane16;     // B row (output col)
            #pragma unroll
            for (int h = 0; h < 2; ++h) {
                int g = h * 4 + kgrp;                     // logical 16B slot
                bv[n][h] = *reinterpret_cast<const i32x4*>(
                    &Bs[cur][0] + tr * ROWB + ((g ^ (tr & 7)) << 4));
            }
        }

        f32x4 acc[4][2] = {};
        __builtin_amdgcn_s_setprio(1);
        #pragma unroll
        for (int h = 0; h < 2; ++h)
            #pragma unroll
            for (int m = 0; m < 4; ++m) {
                i32x8 a8 = __builtin_shufflevector(af[m][h], zeros, 0,1,2,3,4,5,6,7);
                #pragma unroll
                for (int n = 0; n < 2; ++n) {
                    i32x8 b8 = __builtin_shufflevector(bv[n][h], zeros, 0,1,2,3,4,5,6,7);
                    acc[m][n] = __builtin_amdgcn_mfma_scale_f32_16x16x128_f8f6f4(
                        a8, b8, acc[m][n],
                        4, 4,                     // cbsz=fp4(e2m1), blgp=fp4
                        0, SCALE_Q16,             // A scale: 2^-4
                        0, SCALE_Q16);            // B scale: 2^-4
                }
            }
        __builtin_amdgcn_s_setprio(0);

        // stage 2 tiles ahead into the buffer freed at step t-1
        if (t + 2 < NT) stage((cur + 2) % 3, t + 2);

        if (t < NT - 1) {
            // counted drain: stage(t+1) complete; stage(t+2) stays in flight.
            if (t + 2 < NT) asm volatile("s_waitcnt vmcnt(2)" ::: "memory");
            else            asm volatile("s_waitcnt vmcnt(0)" ::: "memory");
            __builtin_amdgcn_sched_barrier(0);
            __builtin_amdgcn_s_barrier();
            __builtin_amdgcn_sched_barrier(0);
        }

        // ---- epilogue: exp2 + mask, accumulate row sums in registers ----
        #pragma unroll
        for (int m = 0; m < 4; ++m) {
            #pragma unroll
            for (int r = 0; r < 4; ++r) {
                float e0 = fast_exp2(acc[m][0][r]);   // == exp(logit/T)
                float e1 = fast_exp2(acc[m][1][r]);
                allp[m][r] += e0 + e1;
                int lr = (labp[m] >> (r * 8)) & 0xFF;
                posp[m][r] += (lr == labc0 ? e0 : 0.0f) + (lr == labc1 ? e1 : 0.0f);
            }
        }

        cur = (cur + 1) % 3;
    }

    // ---- final: reduce across the 16 col-lanes, one atomic per row ----
    #pragma unroll
    for (int m = 0; m < 4; ++m) {
        #pragma unroll
        for (int r = 0; r < 4; ++r) {
            float a = allp[m][r], p = posp[m][r];
            #pragma unroll
            for (int off = 1; off < 16; off <<= 1) {
                a += __shfl_xor(a, off);
                p += __shfl_xor(p, off);
            }
            if (lane16 == 0) {
                int grow = i0 + wr * 64 + m * 16 + kgrp * 4 + r;
                atomicAdd(&all_sum[grow], a);
                atomicAdd(&pos_sum[grow], p);
            }
        }
    }
}

// ------- kernel 3: parallel loss reduction (out pre-zeroed by norm_cast) ----
__global__ void loss_kernel(const float* __restrict__ pos_sum,
                            const float* __restrict__ all_sum,
                            float* __restrict__ out) {
    int gid = blockIdx.x * blockDim.x + threadIdx.x;
    float acc = 0.0f;
    for (int i = gid; i < N_ROWS; i += gridDim.x * blockDim.x)
        acc += logf(pos_sum[i] / all_sum[i]);
    #pragma unroll
    for (int off = 32; off; off >>= 1) acc += __shfl_xor(acc, off);
    __shared__ float red[8];
    int wv = threadIdx.x >> 6, lane = threadIdx.x & 63;
    if (lane == 0) red[wv] = acc;
    __syncthreads();
    if (threadIdx.x == 0) {
        float s = 0.0f;
        #pragma unroll
        for (int w = 0; w < 8; ++w) s += red[w];
        atomicAdd(out, -s / (float)N_ROWS);
    }
}

// ---------------- launch -----------------------------------------------------
extern "C" void kernel_launch(void* const* d_in, const int* in_sizes, int n_in,
                              void* d_out, int out_size, void* d_ws, size_t ws_size,
                              hipStream_t stream) {
    const float* out0   = (const float*)d_in[0];
    const float* out1   = (const float*)d_in[1];
    const int*   labels = (const int*)d_in[2];
    float*       out    = (float*)d_out;

    unsigned char* a_f4 = (unsigned char*)d_ws;
    unsigned char* b_f4 = a_f4 + (size_t)N_ROWS * ROWB;
    float* pos  = (float*)(b_f4 + (size_t)N_ROWS * ROWB);
    float* alls = pos + N_ROWS;

    norm_cast_kernel<<<2 * N_ROWS / 4, 256, 0, stream>>>(out0, out1, a_f4, b_f4, pos, out);

    fused_flash_kernel<<<JSPLIT * (N_ROWS / BM), 256, 0, stream>>>(a_f4, b_f4, labels, pos, alls);

    loss_kernel<<<16, 512, 0, stream>>>(pos, alls, out);
}

// Round 19
// 35.344 us; speedup vs baseline: 1.6586x; 1.0354x over previous
//
#include <hip/hip_runtime.h>
#include <hip/hip_bf16.h>
#include <math.h>

#define N_ROWS 8192
#define D_DIM  256                   // elements; fp4 row = 128 bytes
#define ROWB   128                   // bytes per fp4 row
#define BM 128
#define BN 128
#define JSPLIT 8
#define JRANGE (N_ROWS / JSPLIT)     // 1024
#define NT (JRANGE / BN)             // 8 j-steps per block

typedef __attribute__((ext_vector_type(4))) float f32x4;
typedef __attribute__((ext_vector_type(4))) int   i32x4;
typedef __attribute__((ext_vector_type(8))) int   i32x8;

// logit = dot(na,nb)*2 ; exp(logit) = exp2(dot * 2*log2e).
// fp4 path: quantize na*G with G = sqrt(2*log2e*256) = 27.178; HW scales
// 2^-4 * 2^-4 = 2^-8 -> D = dot * G^2/256 = dot * 2*log2e. exp2(D) direct.
#define CAST_G    27.17835f
#define SCALE_Q16 123                // E8M0: 2^(123-127) = 2^-4

__device__ __forceinline__ float fast_exp2(float x) {
#if __has_builtin(__builtin_amdgcn_exp2f)
    return __builtin_amdgcn_exp2f(x);
#else
    return exp2f(x);
#endif
}

// branchless fp4 e2m1 encode (codes {0,.5,1,1.5,2,3,4,6} are monotone)
__device__ __forceinline__ unsigned int enc_fp4(float x) {
    float a = fabsf(x);
    unsigned int s = (__float_as_uint(x) >> 31) << 3;
    unsigned int c = (a > 0.25f) + (a > 0.75f) + (a > 1.25f) + (a > 1.75f)
                   + (a > 2.5f)  + (a > 3.5f)  + (a > 5.0f);
    return s | c;
}

// ------- kernel 1: L2-normalize rows, scale, cast to fp4 e2m1 (+ zero accum) -
__global__ void norm_cast_kernel(const float* __restrict__ out0,
                                 const float* __restrict__ out1,
                                 unsigned char* __restrict__ a_f4,
                                 unsigned char* __restrict__ b_f4,
                                 float* __restrict__ zero_me,   // pos+all, 2*N floats
                                 float* __restrict__ out) {
    int gtid = blockIdx.x * blockDim.x + threadIdx.x;
    if (gtid < 2 * N_ROWS) zero_me[gtid] = 0.0f;
    if (gtid == 0) out[0] = 0.0f;     // loss kernel accumulates atomically

    int wave = gtid >> 6;
    int lane = threadIdx.x & 63;
    const float* src    = (wave < N_ROWS) ? out0 : out1;
    unsigned char* dst  = (wave < N_ROWS) ? a_f4 : b_f4;
    int row = (wave < N_ROWS) ? wave : wave - N_ROWS;

    float4 v = *reinterpret_cast<const float4*>(src + (size_t)row * D_DIM + lane * 4);
    float ss = v.x * v.x + v.y * v.y + v.z * v.z + v.w * v.w;
    #pragma unroll
    for (int off = 32; off; off >>= 1) ss += __shfl_xor(ss, off);
    float inv = CAST_G / fmaxf(sqrtf(ss), 1e-12f);

    unsigned int p = enc_fp4(v.x * inv)
                   | (enc_fp4(v.y * inv) << 4)
                   | (enc_fp4(v.z * inv) << 8)
                   | (enc_fp4(v.w * inv) << 12);
    *reinterpret_cast<unsigned short*>(dst + (size_t)row * ROWB + lane * 2) =
        (unsigned short)p;
}

// ------- kernel 2: MX-fp4 K=128 fused GEMM + exp2 + masked row-sums ---------
// r18 structure with BN doubled to 128: tile 128x128, wave-tile 64x64
// (m=4 x n=4 x h=2 = 32 MFMA/step), 8 barrier-steps instead of 16 -> per-step
// fixed costs amortize 2x. LDS 3 x 16KB (2 blocks/CU). Triple-buffer, counted
// vmcnt(4), raw s_barrier. Swizzle: 8x16B slots per 128B row,
// LDS[r][phys] = global[r][phys ^ (r&7)]; reads phys = g ^ (tr&7).
__global__ __launch_bounds__(256, 2)
void fused_flash_kernel(const unsigned char* __restrict__ A,
                        const unsigned char* __restrict__ B,
                        const int* __restrict__ labels,
                        float* __restrict__ pos_sum,
                        float* __restrict__ all_sum) {
    __shared__ unsigned char Bs[3][BN * ROWB];   // 3 x 16 KB

    const int tid    = threadIdx.x;
    const int lane   = tid & 63;
    const int wid    = tid >> 6;        // 0..3
    const int wr     = wid >> 1;        // 0..1  (64-row band)
    const int wc     = wid & 1;         // 0..1  (64-col half)
    const int lane16 = lane & 15;
    const int kgrp   = lane >> 4;       // 0..3

    const int jsplit = blockIdx.x & 7;
    const int rowt   = blockIdx.x >> 3;
    const int i0     = rowt * BM;
    const int jbase  = jsplit * JRANGE;

    const i32x4 zeros = {0, 0, 0, 0};

    // ---- A fragments -> registers (once), PINNED (32 VGPR fp4) ----
    // af[m][h]: row = i0+wr*64+m*16+lane16, K [h*128+kgrp*32, +32) = 16 bytes
    i32x4 af[4][2];
    #pragma unroll
    for (int m = 0; m < 4; ++m) {
        const unsigned char* ap =
            A + (size_t)(i0 + wr * 64 + m * 16 + lane16) * ROWB + kgrp * 16;
        #pragma unroll
        for (int h = 0; h < 2; ++h)
            af[m][h] = *reinterpret_cast<const i32x4*>(ap + h * 64);
    }
    #pragma unroll
    for (int m = 0; m < 4; ++m)
        #pragma unroll
        for (int h = 0; h < 2; ++h)
            asm volatile("" : "+v"(af[m][h]));

    // row labels (0..99 fit in a byte), packed 4-per-int, pinned
    int labp[4];
    #pragma unroll
    for (int m = 0; m < 4; ++m) {
        int4 v = *reinterpret_cast<const int4*>(labels + i0 + wr * 64 + m * 16 + kgrp * 4);
        labp[m] = v.x | (v.y << 8) | (v.z << 16) | (v.w << 24);
        asm volatile("" : "+v"(labp[m]));
    }

    // ---- B staging: tile 16KB = 16 chunks of 1KB (8 rows x 128B), 4/wave ----
    auto stage = [&](int buf, int t) {
        const int jrow0 = jbase + t * BN;
        #pragma unroll
        for (int cc = 0; cc < 4; ++cc) {
            int c  = wid * 4 + cc;                  // chunk 0..15 (wave-uniform)
            int gr = jrow0 + c * 8 + (lane >> 3);   // global B row
            const unsigned char* src =
                B + (size_t)gr * ROWB + (((lane & 7) ^ (gr & 7)) << 4);
            __builtin_amdgcn_global_load_lds(
                (const __attribute__((address_space(1))) void*)src,
                (__attribute__((address_space(3))) void*)(&Bs[buf][0] + c * 1024),
                16, 0, 0);
        }
    };

    float allp[4][4] = {};
    float posp[4][4] = {};

    // prologue: stage tiles 0 and 1; drain tile 0 only (vmcnt(4) leaves tile 1)
    stage(0, 0);
    stage(1, 1);
    asm volatile("s_waitcnt vmcnt(4)" ::: "memory");
    __builtin_amdgcn_sched_barrier(0);
    __builtin_amdgcn_s_barrier();
    __builtin_amdgcn_sched_barrier(0);

    int cur = 0;
    for (int t = 0; t < NT; ++t) {
        // column labels early (hide under MFMA)
        int labc[4];
        #pragma unroll
        for (int n = 0; n < 4; ++n)
            labc[n] = labels[jbase + t * BN + wc * 64 + n * 16 + lane16];

        // ---- 8 b128 B-loads, then 32 MFMAs ----
        i32x4 bv[4][2];
        #pragma unroll
        for (int n = 0; n < 4; ++n) {
            const int tr = wc * 64 + n * 16 + lane16;     // B row (output col)
            #pragma unroll
            for (int h = 0; h < 2; ++h) {
                int g = h * 4 + kgrp;                     // logical 16B slot
                bv[n][h] = *reinterpret_cast<const i32x4*>(
                    &Bs[cur][0] + tr * ROWB + ((g ^ (tr & 7)) << 4));
            }
        }

        f32x4 acc[4][4] = {};
        __builtin_amdgcn_s_setprio(1);
        #pragma unroll
        for (int h = 0; h < 2; ++h)
            #pragma unroll
            for (int m = 0; m < 4; ++m) {
                i32x8 a8 = __builtin_shufflevector(af[m][h], zeros, 0,1,2,3,4,5,6,7);
                #pragma unroll
                for (int n = 0; n < 4; ++n) {
                    i32x8 b8 = __builtin_shufflevector(bv[n][h], zeros, 0,1,2,3,4,5,6,7);
                    acc[m][n] = __builtin_amdgcn_mfma_scale_f32_16x16x128_f8f6f4(
                        a8, b8, acc[m][n],
                        4, 4,                     // cbsz=fp4(e2m1), blgp=fp4
                        0, SCALE_Q16,             // A scale: 2^-4
                        0, SCALE_Q16);            // B scale: 2^-4
                }
            }
        __builtin_amdgcn_s_setprio(0);

        // stage 2 tiles ahead into the buffer freed at step t-1
        if (t + 2 < NT) stage((cur + 2) % 3, t + 2);

        if (t < NT - 1) {
            // counted drain: stage(t+1) complete; stage(t+2) stays in flight.
            if (t + 2 < NT) asm volatile("s_waitcnt vmcnt(4)" ::: "memory");
            else            asm volatile("s_waitcnt vmcnt(0)" ::: "memory");
            __builtin_amdgcn_sched_barrier(0);
            __builtin_amdgcn_s_barrier();
            __builtin_amdgcn_sched_barrier(0);
        }

        // ---- epilogue: exp2 + mask, accumulate row sums in registers ----
        #pragma unroll
        for (int m = 0; m < 4; ++m) {
            #pragma unroll
            for (int r = 0; r < 4; ++r) {
                int lr = (labp[m] >> (r * 8)) & 0xFF;
                float ap = 0.0f, pp = 0.0f;
                #pragma unroll
                for (int n = 0; n < 4; ++n) {
                    float e = fast_exp2(acc[m][n][r]);   // == exp(logit/T)
                    ap += e;
                    pp += (lr == labc[n]) ? e : 0.0f;
                }
                allp[m][r] += ap;
                posp[m][r] += pp;
            }
        }

        cur = (cur + 1) % 3;
    }

    // ---- final: reduce across the 16 col-lanes, one atomic per row ----
    #pragma unroll
    for (int m = 0; m < 4; ++m) {
        #pragma unroll
        for (int r = 0; r < 4; ++r) {
            float a = allp[m][r], p = posp[m][r];
            #pragma unroll
            for (int off = 1; off < 16; off <<= 1) {
                a += __shfl_xor(a, off);
                p += __shfl_xor(p, off);
            }
            if (lane16 == 0) {
                int grow = i0 + wr * 64 + m * 16 + kgrp * 4 + r;
                atomicAdd(&all_sum[grow], a);
                atomicAdd(&pos_sum[grow], p);
            }
        }
    }
}

// ------- kernel 3: parallel loss reduction (out pre-zeroed by norm_cast) ----
__global__ void loss_kernel(const float* __restrict__ pos_sum,
                            const float* __restrict__ all_sum,
                            float* __restrict__ out) {
    int gid = blockIdx.x * blockDim.x + threadIdx.x;
    float acc = 0.0f;
    for (int i = gid; i < N_ROWS; i += gridDim.x * blockDim.x)
        acc += logf(pos_sum[i] / all_sum[i]);
    #pragma unroll
    for (int off = 32; off; off >>= 1) acc += __shfl_xor(acc, off);
    __shared__ float red[8];
    int wv = threadIdx.x >> 6, lane = threadIdx.x & 63;
    if (lane == 0) red[wv] = acc;
    __syncthreads();
    if (threadIdx.x == 0) {
        float s = 0.0f;
        #pragma unroll
        for (int w = 0; w < 8; ++w) s += red[w];
        atomicAdd(out, -s / (float)N_ROWS);
    }
}

// ---------------- launch -----------------------------------------------------
extern "C" void kernel_launch(void* const* d_in, const int* in_sizes, int n_in,
                              void* d_out, int out_size, void* d_ws, size_t ws_size,
                              hipStream_t stream) {
    const float* out0   = (const float*)d_in[0];
    const float* out1   = (const float*)d_in[1];
    const int*   labels = (const int*)d_in[2];
    float*       out    = (float*)d_out;

    unsigned char* a_f4 = (unsigned char*)d_ws;
    unsigned char* b_f4 = a_f4 + (size_t)N_ROWS * ROWB;
    float* pos  = (float*)(b_f4 + (size_t)N_ROWS * ROWB);
    float* alls = pos + N_ROWS;

    norm_cast_kernel<<<2 * N_ROWS / 4, 256, 0, stream>>>(out0, out1, a_f4, b_f4, pos, out);

    fused_flash_kernel<<<JSPLIT * (N_ROWS / BM), 256, 0, stream>>>(a_f4, b_f4, labels, pos, alls);

    loss_kernel<<<16, 512, 0, stream>>>(pos, alls, out);
}